// Round 1
// baseline (876.978 us; speedup 1.0000x reference)
//
#include <hip/hip_runtime.h>
#include <hip/hip_bf16.h>

#define DIM 4096
#define HROWS 54
#define HSZ (HROWS * DIM)   // 221184

typedef __attribute__((ext_vector_type(4))) float  f32x4;
typedef __attribute__((ext_vector_type(8))) short  s16x8;

__device__ __forceinline__ short f2bf(float f) {
    union { __hip_bfloat16 h; short s; } u;
    u.h = __float2bfloat16(f);
    return u.s;
}
__device__ __forceinline__ float bf2f(short s) {
    union { __hip_bfloat16 h; short s; } u;
    u.s = s;
    return __bfloat162float(u.h);
}
__device__ __forceinline__ float leaky(float x) { return x > 0.f ? x : 0.01f * x; }

// ---------------------------------------------------------------------------
// GEMM: out[m,n] = sum_k A[m,k] * W[n,k];  A: 54x4096 (padded to 64), W: 4096x4096
// split-K over blockIdx.y (8 slices of 512); writes partial h slices.
// bf16 hi/lo split: 3 MFMAs per tile for ~f32 accuracy.
// ---------------------------------------------------------------------------
__global__ __launch_bounds__(256) void gemm_k(const float* __restrict__ A,
                                              const float* __restrict__ W,
                                              float* __restrict__ outp)
{
    __shared__ short lhi[64 * 64];
    __shared__ short llo[64 * 64];

    const int tid  = threadIdx.x;
    const int lane = tid & 63;
    const int wv   = tid >> 6;       // wave 0..3
    const int nb   = blockIdx.x;     // n-tile (64 cols)
    const int ks   = blockIdx.y;     // k-slice (512)
    const int l15  = lane & 15;
    const int lk8  = lane >> 4;      // 0..3

    const int ncol = nb * 64 + wv * 16 + l15;
    const float* wrow = W + (size_t)ncol * DIM;

    f32x4 acc[4];
#pragma unroll
    for (int mt = 0; mt < 4; ++mt) { acc[mt][0]=0.f; acc[mt][1]=0.f; acc[mt][2]=0.f; acc[mt][3]=0.f; }

    for (int kb = 0; kb < 8; ++kb) {
        const int kg = ks * 512 + kb * 64;
        __syncthreads();
        // stage A[0:64][kg:kg+64] into LDS as bf16 hi/lo, XOR-swizzled chunks
#pragma unroll
        for (int p = 0; p < 2; ++p) {
            const int id  = p * 256 + tid;   // 0..511
            const int row = id >> 3;
            const int ch  = id & 7;
            f32x4 a0, a1;
            if (row < HROWS) {
                const float* g = A + (size_t)row * DIM + kg + ch * 8;
                a0 = *(const f32x4*)g;
                a1 = *(const f32x4*)(g + 4);
            } else {
                a0 = (f32x4){0.f,0.f,0.f,0.f};
                a1 = (f32x4){0.f,0.f,0.f,0.f};
            }
            s16x8 vh, vl;
#pragma unroll
            for (int j = 0; j < 4; ++j) {
                short h0 = f2bf(a0[j]); vh[j]   = h0; vl[j]   = f2bf(a0[j] - bf2f(h0));
                short h1 = f2bf(a1[j]); vh[4+j] = h1; vl[4+j] = f2bf(a1[j] - bf2f(h1));
            }
            const int sch = ch ^ (row & 7);
            *(s16x8*)&lhi[row * 64 + sch * 8] = vh;
            *(s16x8*)&llo[row * 64 + sch * 8] = vl;
        }
        __syncthreads();

        // B (W) loads for both 32-k steps of this BK=64
        const float* wp = wrow + kg + lk8 * 8;
        const f32x4 b00 = *(const f32x4*)(wp);
        const f32x4 b01 = *(const f32x4*)(wp + 4);
        const f32x4 b10 = *(const f32x4*)(wp + 32);
        const f32x4 b11 = *(const f32x4*)(wp + 36);

#pragma unroll
        for (int kk = 0; kk < 2; ++kk) {
            const f32x4 c0 = kk ? b10 : b00;
            const f32x4 c1 = kk ? b11 : b01;
            s16x8 bh, bl;
#pragma unroll
            for (int j = 0; j < 4; ++j) {
                short h0 = f2bf(c0[j]); bh[j]   = h0; bl[j]   = f2bf(c0[j] - bf2f(h0));
                short h1 = f2bf(c1[j]); bh[4+j] = h1; bl[4+j] = f2bf(c1[j] - bf2f(h1));
            }
#pragma unroll
            for (int mt = 0; mt < 4; ++mt) {
                const int row = mt * 16 + l15;
                const int sch = (kk * 4 + lk8) ^ (row & 7);
                const s16x8 ah = *(const s16x8*)&lhi[row * 64 + sch * 8];
                const s16x8 al = *(const s16x8*)&llo[row * 64 + sch * 8];
                acc[mt] = __builtin_amdgcn_mfma_f32_16x16x32_bf16(ah, bh, acc[mt], 0, 0, 0);
                acc[mt] = __builtin_amdgcn_mfma_f32_16x16x32_bf16(al, bh, acc[mt], 0, 0, 0);
                acc[mt] = __builtin_amdgcn_mfma_f32_16x16x32_bf16(ah, bl, acc[mt], 0, 0, 0);
            }
        }
    }

    float* op = outp + (size_t)ks * HSZ;
#pragma unroll
    for (int mt = 0; mt < 4; ++mt) {
#pragma unroll
        for (int r = 0; r < 4; ++r) {
            const int m = mt * 16 + lk8 * 4 + r;
            if (m < HROWS) op[(size_t)m * DIM + ncol] = acc[mt][r];
        }
    }
}

// ---------------------------------------------------------------------------
// dots[r][v] = sum_k h[r,k] * wvec[v][k], v in {if1,if2,fd1,fd2,dr1,dr2}
// h reduced on the fly from 8 split-K partials.
// ---------------------------------------------------------------------------
__global__ __launch_bounds__(256) void dots_k(const float* __restrict__ hpart,
                                              const float* __restrict__ wif,
                                              const float* __restrict__ wfd,
                                              const float* __restrict__ wdr,
                                              float* __restrict__ dots)
{
    const int r   = blockIdx.x;   // 0..53
    const int tid = threadIdx.x;
    float a0=0,a1=0,a2=0,a3=0,a4=0,a5=0;
    const float* hr = hpart + (size_t)r * DIM;
    for (int k = tid; k < DIM; k += 256) {
        float h = 0.f;
#pragma unroll
        for (int s = 0; s < 8; ++s) h += hr[(size_t)s * HSZ + k];
        a0 += h * wif[k];       a1 += h * wif[DIM + k];
        a2 += h * wfd[k];       a3 += h * wfd[DIM + k];
        a4 += h * wdr[k];       a5 += h * wdr[DIM + k];
    }
#pragma unroll
    for (int off = 32; off > 0; off >>= 1) {
        a0 += __shfl_down(a0, off); a1 += __shfl_down(a1, off);
        a2 += __shfl_down(a2, off); a3 += __shfl_down(a3, off);
        a4 += __shfl_down(a4, off); a5 += __shfl_down(a5, off);
    }
    __shared__ float red[4][6];
    if ((tid & 63) == 0) {
        const int w = tid >> 6;
        red[w][0]=a0; red[w][1]=a1; red[w][2]=a2; red[w][3]=a3; red[w][4]=a4; red[w][5]=a5;
    }
    __syncthreads();
    if (tid < 6) dots[r * 6 + tid] = red[0][tid] + red[1][tid] + red[2][tid] + red[3][tid];
}

// ---------------------------------------------------------------------------
// Build the 54x54 mixing matrix T (x' = T @ h) from the dots.
// Tree topology hard-coded (deterministic in setup_inputs).
// ---------------------------------------------------------------------------
__global__ __launch_bounds__(64) void tmat_k(const float* __restrict__ dots,
                                             float* __restrict__ T)
{
    __shared__ float Ts[54][54];
    __shared__ float ad0[5], adc[12], ar[6];
    const int tid = threadIdx.x;
    for (int i = tid; i < 54 * 54; i += 64) ((float*)Ts)[i] = 0.f;
    __syncthreads();

    if (tid == 0) {
        float fdot3[12], fdot5[12], ddot5[5];
        // level if: facets (rows 6..17) over ideos (rows 18..53), children of p = {3p,3p+1,3p+2}
        for (int p = 0; p < 12; ++p) {
            const float u = dots[(6+p)*6 + 0];
            const float ss = leaky(u + dots[(6+p)*6 + 1]);
            float sc[3], mx = ss;
            for (int j = 0; j < 3; ++j) { sc[j] = leaky(u + dots[(18+3*p+j)*6 + 1]); mx = fmaxf(mx, sc[j]); }
            float e0 = expf(ss - mx), s = e0, ec[3];
            for (int j = 0; j < 3; ++j) { ec[j] = expf(sc[j] - mx); s += ec[j]; }
            const float inv = 1.f / s;
            const float a0 = e0 * inv;
            float f3 = a0 * dots[(6+p)*6 + 3];
            float f5 = a0 * dots[(6+p)*6 + 5];
            Ts[6+p][6+p] = a0;
            for (int j = 0; j < 3; ++j) {
                const float a = ec[j] * inv;
                Ts[6+p][18+3*p+j] = a;
                f3 += a * dots[(18+3*p+j)*6 + 3];
                f5 += a * dots[(18+3*p+j)*6 + 5];
            }
            fdot3[p] = f3; fdot5[p] = f5;
        }
        // level fd: domains (rows 1..5) over fac_new; children per dom: {3,2,3,2,2}
        const int cstart[5] = {0,3,5,8,10};
        const int ccnt[5]   = {3,2,3,2,2};
#pragma unroll
        for (int p = 0; p < 5; ++p) {
            const float u = dots[(1+p)*6 + 2];
            const float ss = leaky(u + dots[(1+p)*6 + 3]);
            float mx = ss, sc[3];
            const int n = ccnt[p], c0 = cstart[p];
            for (int j = 0; j < n; ++j) { sc[j] = leaky(u + fdot3[c0+j]); mx = fmaxf(mx, sc[j]); }
            float e0 = expf(ss - mx), s = e0, ec[3];
            for (int j = 0; j < n; ++j) { ec[j] = expf(sc[j] - mx); s += ec[j]; }
            const float inv = 1.f / s;
            ad0[p] = e0 * inv;
            float d5 = ad0[p] * dots[(1+p)*6 + 5];
            for (int j = 0; j < n; ++j) {
                const float a = ec[j] * inv;
                adc[c0+j] = a;
                d5 += a * fdot5[c0+j];
            }
            ddot5[p] = d5;
        }
        // level dr: root over dom_new (5 children)
        {
            const float u = dots[0*6 + 4];
            const float ss = leaky(u + dots[0*6 + 5]);
            float mx = ss, sc[5];
            for (int d = 0; d < 5; ++d) { sc[d] = leaky(u + ddot5[d]); mx = fmaxf(mx, sc[d]); }
            float e0 = expf(ss - mx), s = e0, ec[5];
            for (int d = 0; d < 5; ++d) { ec[d] = expf(sc[d] - mx); s += ec[d]; }
            const float inv = 1.f / s;
            ar[0] = e0 * inv;
            for (int d = 0; d < 5; ++d) ar[1+d] = ec[d] * inv;
        }
        // identity for ideo rows
        for (int q = 0; q < 36; ++q) Ts[18+q][18+q] = 1.f;
    }
    __syncthreads();

    if (tid < 54) {
        const int j = tid;
        const int cstart[5] = {0,3,5,8,10};
        const int ccnt[5]   = {3,2,3,2,2};
        for (int p = 0; p < 5; ++p) {
            float t = ad0[p] * ((j == 1+p) ? 1.f : 0.f);
            for (int c = cstart[p]; c < cstart[p] + ccnt[p]; ++c) t += adc[c] * Ts[6+c][j];
            Ts[1+p][j] = t;
        }
    }
    __syncthreads();
    if (tid < 54) {
        float t = ar[0] * ((tid == 0) ? 1.f : 0.f);
        for (int d = 0; d < 5; ++d) t += ar[1+d] * Ts[1+d][tid];
        Ts[0][tid] = t;
    }
    __syncthreads();
    for (int i = tid; i < 54 * 54; i += 64) T[i] = ((float*)Ts)[i];
}

// ---------------------------------------------------------------------------
// x' = T @ h  (h reduced from 8 partials on the fly), one column per thread.
// ---------------------------------------------------------------------------
__global__ __launch_bounds__(256) void applyT_k(const float* __restrict__ hpart,
                                                const float* __restrict__ T,
                                                float* __restrict__ xo)
{
    __shared__ float Ts[54 * 54];
    const int tid = threadIdx.x;
    for (int i = tid; i < 54 * 54; i += 256) Ts[i] = T[i];
    __syncthreads();
    const int k = blockIdx.x * 256 + tid;
    float h[54];
#pragma unroll
    for (int r = 0; r < 54; ++r) {
        float s = 0.f;
#pragma unroll
        for (int sl = 0; sl < 8; ++sl) s += hpart[(size_t)sl * HSZ + (size_t)r * DIM + k];
        h[r] = s;
    }
#pragma unroll 1
    for (int m = 0; m < 54; ++m) {
        float o = 0.f;
#pragma unroll
        for (int r = 0; r < 54; ++r) o += Ts[m * 54 + r] * h[r];
        xo[(size_t)m * DIM + k] = o;
    }
}

// ---------------------------------------------------------------------------
// RoPE-style tree propagation on h2 (reduced from 8 partials), writes next x.
// Column j pairs (j, j+2048). Parent maps hard-coded.
// ---------------------------------------------------------------------------
__device__ __forceinline__ float sum8(const float* __restrict__ hpart, int r, int c)
{
    float s = 0.f;
#pragma unroll
    for (int sl = 0; sl < 8; ++sl) s += hpart[(size_t)sl * HSZ + (size_t)r * DIM + c];
    return s;
}

__global__ __launch_bounds__(256) void rope_k(const float* __restrict__ hpart,
                                              const float* __restrict__ edge,
                                              float* __restrict__ xo)
{
    const int j = blockIdx.x * 256 + threadIdx.x;   // 0..2047
    const float e0 = edge[j], e1 = edge[2048 + j], e2 = edge[4096 + j];
    const float er0 = cosf(e0), ei0 = sinf(e0);
    const float er1 = cosf(e1), ei1 = sinf(e1);
    const float er2 = cosf(e2), ei2 = sinf(e2);

    const float rr = sum8(hpart, 0, j);
    const float ri = sum8(hpart, 0, j + 2048);
    xo[j] = rr;
    xo[2048 + j] = ri;

    float dr[5], di[5];
#pragma unroll
    for (int p = 0; p < 5; ++p) {
        dr[p] = sum8(hpart, 1 + p, j)        + rr * er0 - ri * ei0;
        di[p] = sum8(hpart, 1 + p, j + 2048) + rr * ei0 + ri * er0;
        xo[(size_t)(1 + p) * DIM + j]        = dr[p] * 0.5f;
        xo[(size_t)(1 + p) * DIM + 2048 + j] = di[p] * 0.5f;
    }
    constexpr int PF[12] = {0,0,0,1,1,2,2,2,3,3,4,4};
    float fr[12], fi[12];
#pragma unroll
    for (int c = 0; c < 12; ++c) {
        const int p = PF[c];
        fr[c] = sum8(hpart, 6 + c, j)        + dr[p] * er1 - di[p] * ei1;
        fi[c] = sum8(hpart, 6 + c, j + 2048) + dr[p] * ei1 + di[p] * er1;
        xo[(size_t)(6 + c) * DIM + j]        = fr[c] * (1.f / 3.f);
        xo[(size_t)(6 + c) * DIM + 2048 + j] = fi[c] * (1.f / 3.f);
    }
#pragma unroll
    for (int q = 0; q < 36; ++q) {
        const int f = q / 3;
        const float irv = sum8(hpart, 18 + q, j)        + fr[f] * er2 - fi[f] * ei2;
        const float iiv = sum8(hpart, 18 + q, j + 2048) + fr[f] * ei2 + fi[f] * er2;
        xo[(size_t)(18 + q) * DIM + j]        = irv * 0.25f;
        xo[(size_t)(18 + q) * DIM + 2048 + j] = iiv * 0.25f;
    }
}

// ---------------------------------------------------------------------------
extern "C" void kernel_launch(void* const* d_in, const int* in_sizes, int n_in,
                              void* d_out, int out_size, void* d_ws, size_t ws_size,
                              hipStream_t stream)
{
    const float* ce    = (const float*)d_in[0];
    const float* gatW  = (const float*)d_in[1];
    const float* attif = (const float*)d_in[2];
    const float* attfd = (const float*)d_in[3];
    const float* attdr = (const float*)d_in[4];
    const float* metaW = (const float*)d_in[5];
    const float* edge  = (const float*)d_in[6];
    float* out = (float*)d_out;

    float* ws    = (float*)d_ws;
    float* hpart = ws;                       // 8 * 221184
    float* x1    = hpart + 8 * HSZ;          // 221184
    float* x2    = x1 + HSZ;                 // 221184
    float* dots  = x2 + HSZ;                 // 512 (324 used)
    float* Tm    = dots + 512;               // 3072 (2916 used)

    for (int i = 0; i < 4; ++i) {
        const float* xin = (i == 0) ? ce : x1;
        hipLaunchKernelGGL(gemm_k, dim3(64, 8), dim3(256), 0, stream,
                           xin, gatW + (size_t)i * DIM * DIM, hpart);
        hipLaunchKernelGGL(dots_k, dim3(54), dim3(256), 0, stream,
                           hpart, attif + (size_t)i * 2 * DIM, attfd + (size_t)i * 2 * DIM,
                           attdr + (size_t)i * 2 * DIM, dots);
        hipLaunchKernelGGL(tmat_k, dim3(1), dim3(64), 0, stream, dots, Tm);
        hipLaunchKernelGGL(applyT_k, dim3(16), dim3(256), 0, stream, hpart, Tm, x2);
        hipLaunchKernelGGL(gemm_k, dim3(64, 8), dim3(256), 0, stream,
                           x2, metaW + (size_t)i * DIM * DIM, hpart);
        hipLaunchKernelGGL(rope_k, dim3(8), dim3(256), 0, stream,
                           hpart, edge, (i == 3) ? out : x1);
    }
}

// Round 3
// 469.779 us; speedup vs baseline: 1.8668x; 1.8668x over previous
//
#include <hip/hip_runtime.h>
#include <hip/hip_bf16.h>

#define DIM 4096
#define HROWS 54
#define HSZ (HROWS * DIM)   // 221184
#define SPLITK 8

typedef __attribute__((ext_vector_type(4))) float  f32x4;
typedef __attribute__((ext_vector_type(8))) short  s16x8;

__device__ __forceinline__ short f2bf(float f) {
    union { __hip_bfloat16 h; short s; } u;
    u.h = __float2bfloat16(f);
    return u.s;
}
__device__ __forceinline__ float bf2f(short s) {
    union { __hip_bfloat16 h; short s; } u;
    u.s = s;
    return __bfloat162float(u.h);
}
__device__ __forceinline__ float leaky(float x) { return x > 0.f ? x : 0.01f * x; }

// split 8 f32 -> bf16 hi + bf16 lo-residual
__device__ __forceinline__ void split8(const f32x4& c0, const f32x4& c1,
                                       s16x8& h, s16x8& l) {
#pragma unroll
    for (int j = 0; j < 4; ++j) {
        short h0 = f2bf(c0[j]); h[j]     = h0; l[j]     = f2bf(c0[j] - bf2f(h0));
        short h1 = f2bf(c1[j]); h[4 + j] = h1; l[4 + j] = f2bf(c1[j] - bf2f(h1));
    }
}

// ---------------------------------------------------------------------------
// prep: concept_embed -> bf16 hi/lo (padded to 64 rows), zero pads of x1/x2,
// trig tables for the edge embeddings.  idx grid: 64*4096 = 262144.
// ---------------------------------------------------------------------------
__global__ __launch_bounds__(256) void prep_k(const float* __restrict__ ce,
                                              const float* __restrict__ edge,
                                              short* __restrict__ ah, short* __restrict__ al,
                                              short* __restrict__ x1h, short* __restrict__ x1l,
                                              short* __restrict__ x2h, short* __restrict__ x2l,
                                              float* __restrict__ er, float* __restrict__ ei)
{
    const int idx = blockIdx.x * 256 + threadIdx.x;
    const int row = idx >> 12;
    const float v = (row < HROWS) ? ce[idx] : 0.f;
    const short h = f2bf(v);
    ah[idx] = h;
    al[idx] = f2bf(v - bf2f(h));
    if (row >= HROWS) { x1h[idx] = 0; x1l[idx] = 0; x2h[idx] = 0; x2l[idx] = 0; }
    if (idx < 3 * 2048) {
        const float e = edge[idx];
        er[idx] = cosf(e);
        ei[idx] = sinf(e);
    }
}

// ---------------------------------------------------------------------------
// GEMM: out[m,n] = sum_k A[m,k]*W[n,k]; A pre-split bf16 hi/lo [64][4096],
// W f32 streamed. Barrier-free, LDS-free: A frags are L2-hit gathers.
// split-K over blockIdx.y (8 slices of 512). 3-MFMA hi/lo for ~f32 accuracy.
// ---------------------------------------------------------------------------
__global__ __launch_bounds__(256, 2) void gemm_k(const short* __restrict__ Ah,
                                                 const short* __restrict__ Al,
                                                 const float* __restrict__ W,
                                                 float* __restrict__ outp)
{
    const int tid  = threadIdx.x;
    const int lane = tid & 63;
    const int wv   = tid >> 6;       // wave 0..3
    const int nb   = blockIdx.x;     // n-tile (64 cols)
    const int ks   = blockIdx.y;     // k-slice (512)
    const int l15  = lane & 15;
    const int lk8  = lane >> 4;      // 0..3

    const int ncol = nb * 64 + wv * 16 + l15;
    const int k0   = ks * 512 + lk8 * 8;
    const float* wp = W + (size_t)ncol * DIM + k0;

    const short* ah0 = Ah + (size_t)(0 * 16 + l15) * DIM + k0;
    const short* ah1 = Ah + (size_t)(1 * 16 + l15) * DIM + k0;
    const short* ah2 = Ah + (size_t)(2 * 16 + l15) * DIM + k0;
    const short* ah3 = Ah + (size_t)(3 * 16 + l15) * DIM + k0;
    const short* al0 = Al + (size_t)(0 * 16 + l15) * DIM + k0;
    const short* al1 = Al + (size_t)(1 * 16 + l15) * DIM + k0;
    const short* al2 = Al + (size_t)(2 * 16 + l15) * DIM + k0;
    const short* al3 = Al + (size_t)(3 * 16 + l15) * DIM + k0;

    f32x4 acc0 = {0.f,0.f,0.f,0.f}, acc1 = {0.f,0.f,0.f,0.f};
    f32x4 acc2 = {0.f,0.f,0.f,0.f}, acc3 = {0.f,0.f,0.f,0.f};

#pragma unroll
    for (int kb = 0; kb < 8; ++kb) {
        const int ko = kb * 64;                       // element offset within slice
        const f32x4 b00 = *(const f32x4*)(wp + ko);
        const f32x4 b01 = *(const f32x4*)(wp + ko + 4);
        const f32x4 b10 = *(const f32x4*)(wp + ko + 32);
        const f32x4 b11 = *(const f32x4*)(wp + ko + 36);

#pragma unroll
        for (int kk = 0; kk < 2; ++kk) {
            s16x8 bh, bl;
            split8(kk ? b10 : b00, kk ? b11 : b01, bh, bl);
            const int ao = ko + kk * 32;
            const s16x8 a0h = *(const s16x8*)(ah0 + ao);
            const s16x8 a1h = *(const s16x8*)(ah1 + ao);
            const s16x8 a2h = *(const s16x8*)(ah2 + ao);
            const s16x8 a3h = *(const s16x8*)(ah3 + ao);
            const s16x8 a0l = *(const s16x8*)(al0 + ao);
            const s16x8 a1l = *(const s16x8*)(al1 + ao);
            const s16x8 a2l = *(const s16x8*)(al2 + ao);
            const s16x8 a3l = *(const s16x8*)(al3 + ao);
            acc0 = __builtin_amdgcn_mfma_f32_16x16x32_bf16(a0h, bh, acc0, 0, 0, 0);
            acc1 = __builtin_amdgcn_mfma_f32_16x16x32_bf16(a1h, bh, acc1, 0, 0, 0);
            acc2 = __builtin_amdgcn_mfma_f32_16x16x32_bf16(a2h, bh, acc2, 0, 0, 0);
            acc3 = __builtin_amdgcn_mfma_f32_16x16x32_bf16(a3h, bh, acc3, 0, 0, 0);
            acc0 = __builtin_amdgcn_mfma_f32_16x16x32_bf16(a0l, bh, acc0, 0, 0, 0);
            acc1 = __builtin_amdgcn_mfma_f32_16x16x32_bf16(a1l, bh, acc1, 0, 0, 0);
            acc2 = __builtin_amdgcn_mfma_f32_16x16x32_bf16(a2l, bh, acc2, 0, 0, 0);
            acc3 = __builtin_amdgcn_mfma_f32_16x16x32_bf16(a3l, bh, acc3, 0, 0, 0);
            acc0 = __builtin_amdgcn_mfma_f32_16x16x32_bf16(a0h, bl, acc0, 0, 0, 0);
            acc1 = __builtin_amdgcn_mfma_f32_16x16x32_bf16(a1h, bl, acc1, 0, 0, 0);
            acc2 = __builtin_amdgcn_mfma_f32_16x16x32_bf16(a2h, bl, acc2, 0, 0, 0);
            acc3 = __builtin_amdgcn_mfma_f32_16x16x32_bf16(a3h, bl, acc3, 0, 0, 0);
        }
    }

    float* op = outp + (size_t)blockIdx.y * HSZ;
#pragma unroll
    for (int mt = 0; mt < 4; ++mt) {
        const f32x4 a = (mt == 0) ? acc0 : (mt == 1) ? acc1 : (mt == 2) ? acc2 : acc3;
#pragma unroll
        for (int r = 0; r < 4; ++r) {
            const int m = mt * 16 + lk8 * 4 + r;
            if (m < HROWS) op[(size_t)m * DIM + ncol] = a[r];
        }
    }
}

// ---------------------------------------------------------------------------
// hsum: reduce the 8 split-K partials (wide, BW-bound).
// ---------------------------------------------------------------------------
__global__ __launch_bounds__(256) void hsum_k(const float* __restrict__ hpart,
                                              float* __restrict__ hsum)
{
    const size_t i = ((size_t)blockIdx.x * 256 + threadIdx.x) * 4;   // 216 blocks
    f32x4 s = {0.f,0.f,0.f,0.f};
#pragma unroll
    for (int sl = 0; sl < SPLITK; ++sl) s += *(const f32x4*)(hpart + (size_t)sl * HSZ + i);
    *(f32x4*)(hsum + i) = s;
}

// ---------------------------------------------------------------------------
// dots[r][v] = h[r] . wvec[v], v in {if1,if2,fd1,fd2,dr1,dr2}  (h = hsum, L2)
// ---------------------------------------------------------------------------
__global__ __launch_bounds__(256) void dots_k(const float* __restrict__ h,
                                              const float* __restrict__ wif,
                                              const float* __restrict__ wfd,
                                              const float* __restrict__ wdr,
                                              float* __restrict__ dots)
{
    const int r   = blockIdx.x;   // 0..53
    const int tid = threadIdx.x;
    float a0=0,a1=0,a2=0,a3=0,a4=0,a5=0;
    const float* hr = h + (size_t)r * DIM;
    for (int k = tid; k < DIM; k += 256) {
        const float hv = hr[k];
        a0 += hv * wif[k];       a1 += hv * wif[DIM + k];
        a2 += hv * wfd[k];       a3 += hv * wfd[DIM + k];
        a4 += hv * wdr[k];       a5 += hv * wdr[DIM + k];
    }
#pragma unroll
    for (int off = 32; off > 0; off >>= 1) {
        a0 += __shfl_down(a0, off); a1 += __shfl_down(a1, off);
        a2 += __shfl_down(a2, off); a3 += __shfl_down(a3, off);
        a4 += __shfl_down(a4, off); a5 += __shfl_down(a5, off);
    }
    __shared__ float red[4][6];
    if ((tid & 63) == 0) {
        const int w = tid >> 6;
        red[w][0]=a0; red[w][1]=a1; red[w][2]=a2; red[w][3]=a3; red[w][4]=a4; red[w][5]=a5;
    }
    __syncthreads();
    if (tid < 6) dots[r * 6 + tid] = red[0][tid] + red[1][tid] + red[2][tid] + red[3][tid];
}

// ---------------------------------------------------------------------------
// Build the 54x54 mixing matrix T (x' = T @ h). Tree topology hard-coded.
// ---------------------------------------------------------------------------
__global__ __launch_bounds__(64) void tmat_k(const float* __restrict__ dots,
                                             float* __restrict__ T)
{
    __shared__ float Ts[54][54];
    __shared__ float ad0[5], adc[12], ar[6];
    const int tid = threadIdx.x;
    for (int i = tid; i < 54 * 54; i += 64) ((float*)Ts)[i] = 0.f;
    __syncthreads();

    if (tid == 0) {
        float fdot3[12], fdot5[12], ddot5[5];
        for (int p = 0; p < 12; ++p) {
            const float u = dots[(6+p)*6 + 0];
            const float ss = leaky(u + dots[(6+p)*6 + 1]);
            float sc[3], mx = ss;
            for (int j = 0; j < 3; ++j) { sc[j] = leaky(u + dots[(18+3*p+j)*6 + 1]); mx = fmaxf(mx, sc[j]); }
            float e0 = expf(ss - mx), s = e0, ec[3];
            for (int j = 0; j < 3; ++j) { ec[j] = expf(sc[j] - mx); s += ec[j]; }
            const float inv = 1.f / s;
            const float a0 = e0 * inv;
            float f3 = a0 * dots[(6+p)*6 + 3];
            float f5 = a0 * dots[(6+p)*6 + 5];
            Ts[6+p][6+p] = a0;
            for (int j = 0; j < 3; ++j) {
                const float a = ec[j] * inv;
                Ts[6+p][18+3*p+j] = a;
                f3 += a * dots[(18+3*p+j)*6 + 3];
                f5 += a * dots[(18+3*p+j)*6 + 5];
            }
            fdot3[p] = f3; fdot5[p] = f5;
        }
        const int cstart[5] = {0,3,5,8,10};
        const int ccnt[5]   = {3,2,3,2,2};
#pragma unroll
        for (int p = 0; p < 5; ++p) {
            const float u = dots[(1+p)*6 + 2];
            const float ss = leaky(u + dots[(1+p)*6 + 3]);
            float mx = ss, sc[3];
            const int n = ccnt[p], c0 = cstart[p];
            for (int j = 0; j < n; ++j) { sc[j] = leaky(u + fdot3[c0+j]); mx = fmaxf(mx, sc[j]); }
            float e0 = expf(ss - mx), s = e0, ec[3];
            for (int j = 0; j < n; ++j) { ec[j] = expf(sc[j] - mx); s += ec[j]; }
            const float inv = 1.f / s;
            ad0[p] = e0 * inv;
            float d5 = ad0[p] * dots[(1+p)*6 + 5];
            for (int j = 0; j < n; ++j) {
                const float a = ec[j] * inv;
                adc[c0+j] = a;
                d5 += a * fdot5[c0+j];
            }
            ddot5[p] = d5;
        }
        {
            const float u = dots[0*6 + 4];
            const float ss = leaky(u + dots[0*6 + 5]);
            float mx = ss, sc[5];
            for (int d = 0; d < 5; ++d) { sc[d] = leaky(u + ddot5[d]); mx = fmaxf(mx, sc[d]); }
            float e0 = expf(ss - mx), s = e0, ec[5];
            for (int d = 0; d < 5; ++d) { ec[d] = expf(sc[d] - mx); s += ec[d]; }
            const float inv = 1.f / s;
            ar[0] = e0 * inv;
            for (int d = 0; d < 5; ++d) ar[1+d] = ec[d] * inv;
        }
        for (int q = 0; q < 36; ++q) Ts[18+q][18+q] = 1.f;
    }
    __syncthreads();

    if (tid < 54) {
        const int j = tid;
        const int cstart[5] = {0,3,5,8,10};
        const int ccnt[5]   = {3,2,3,2,2};
        for (int p = 0; p < 5; ++p) {
            float t = ad0[p] * ((j == 1+p) ? 1.f : 0.f);
            for (int c = cstart[p]; c < cstart[p] + ccnt[p]; ++c) t += adc[c] * Ts[6+c][j];
            Ts[1+p][j] = t;
        }
    }
    __syncthreads();
    if (tid < 54) {
        float t = ar[0] * ((tid == 0) ? 1.f : 0.f);
        for (int d = 0; d < 5; ++d) t += ar[1+d] * Ts[1+d][tid];
        Ts[0][tid] = t;
    }
    __syncthreads();
    for (int i = tid; i < 54 * 54; i += 64) T[i] = ((float*)Ts)[i];
}

// ---------------------------------------------------------------------------
// x2 = T @ h, written directly as bf16 hi/lo. block = (k-tile, m). 864 blocks.
// ---------------------------------------------------------------------------
__global__ __launch_bounds__(256) void applyT_k(const float* __restrict__ h,
                                                const float* __restrict__ T,
                                                short* __restrict__ xh,
                                                short* __restrict__ xl)
{
    const int m = blockIdx.y;                      // 0..53
    const int k = blockIdx.x * 256 + threadIdx.x;  // 0..4095
    float o = 0.f;
#pragma unroll
    for (int r = 0; r < HROWS; ++r) o += T[m * HROWS + r] * h[(size_t)r * DIM + k];
    const short hi = f2bf(o);
    xh[(size_t)m * DIM + k] = hi;
    xl[(size_t)m * DIM + k] = f2bf(o - bf2f(hi));
}

// ---------------------------------------------------------------------------
// RoPE tree propagation, wide: block = (j-tile, output row r). Each thread
// recomputes its ancestor chain (all reads L2-resident).
// ---------------------------------------------------------------------------
__global__ __launch_bounds__(256) void rope_k(const float* __restrict__ h,
                                              const float* __restrict__ er,
                                              const float* __restrict__ ei,
                                              short* __restrict__ xh,
                                              short* __restrict__ xl,
                                              float* __restrict__ xo,
                                              int last)
{
    const int r = blockIdx.y;                       // 0..53
    const int j = blockIdx.x * 256 + threadIdx.x;   // 0..2047
    constexpr int PF[12] = {0,0,0,1,1,2,2,2,3,3,4,4};

    const float rr = h[j], ri = h[2048 + j];
    float vr, vi, scale;
    if (r == 0) {
        vr = rr; vi = ri; scale = 1.f;
    } else {
        const float er0 = er[j], ei0 = ei[j];
        int p, c;
        if (r < 6)       { p = r - 1;  c = -1; }
        else if (r < 18) { c = r - 6;  p = PF[c]; }
        else             { c = (r - 18) / 3; p = PF[c]; }
        const float hdr = h[(size_t)(1 + p) * DIM + j];
        const float hdi = h[(size_t)(1 + p) * DIM + 2048 + j];
        const float dr = hdr + rr * er0 - ri * ei0;
        const float di = hdi + rr * ei0 + ri * er0;
        if (r < 6) {
            vr = dr; vi = di; scale = 0.5f;
        } else {
            const float er1 = er[2048 + j], ei1 = ei[2048 + j];
            const float hfr = h[(size_t)(6 + c) * DIM + j];
            const float hfi = h[(size_t)(6 + c) * DIM + 2048 + j];
            const float fr = hfr + dr * er1 - di * ei1;
            const float fi = hfi + dr * ei1 + di * er1;
            if (r < 18) {
                vr = fr; vi = fi; scale = 1.f / 3.f;
            } else {
                const float er2 = er[4096 + j], ei2 = ei[4096 + j];
                vr = h[(size_t)r * DIM + j]        + fr * er2 - fi * ei2;
                vi = h[(size_t)r * DIM + 2048 + j] + fr * ei2 + fi * er2;
                scale = 0.25f;
            }
        }
    }
    vr *= scale; vi *= scale;
    if (last) {
        xo[(size_t)r * DIM + j]        = vr;
        xo[(size_t)r * DIM + 2048 + j] = vi;
    } else {
        const short h0 = f2bf(vr);
        xh[(size_t)r * DIM + j] = h0;
        xl[(size_t)r * DIM + j] = f2bf(vr - bf2f(h0));
        const short h1 = f2bf(vi);
        xh[(size_t)r * DIM + 2048 + j] = h1;
        xl[(size_t)r * DIM + 2048 + j] = f2bf(vi - bf2f(h1));
    }
}

// ---------------------------------------------------------------------------
extern "C" void kernel_launch(void* const* d_in, const int* in_sizes, int n_in,
                              void* d_out, int out_size, void* d_ws, size_t ws_size,
                              hipStream_t stream)
{
    const float* ce    = (const float*)d_in[0];
    const float* gatW  = (const float*)d_in[1];
    const float* attif = (const float*)d_in[2];
    const float* attfd = (const float*)d_in[3];
    const float* attdr = (const float*)d_in[4];
    const float* metaW = (const float*)d_in[5];
    const float* edge  = (const float*)d_in[6];
    float* out = (float*)d_out;

    char* w = (char*)d_ws;
    float* hpart = (float*)w;                 w += (size_t)SPLITK * HSZ * 4;   // 7.08 MB
    float* hsum  = (float*)w;                 w += (size_t)HSZ * 4;            // 884 KB
    float* dots  = (float*)w;                 w += 2048;
    float* Tm    = (float*)w;                 w += 16384;
    float* er    = (float*)w;                 w += 3 * 2048 * 4;
    float* ei    = (float*)w;                 w += 3 * 2048 * 4;
    short* a0h   = (short*)w;                 w += (size_t)64 * DIM * 2;       // 512 KB each
    short* a0l   = (short*)w;                 w += (size_t)64 * DIM * 2;
    short* x1h   = (short*)w;                 w += (size_t)64 * DIM * 2;
    short* x1l   = (short*)w;                 w += (size_t)64 * DIM * 2;
    short* x2h   = (short*)w;                 w += (size_t)64 * DIM * 2;
    short* x2l   = (short*)w;                 w += (size_t)64 * DIM * 2;

    hipLaunchKernelGGL(prep_k, dim3(1024), dim3(256), 0, stream,
                       ce, edge, a0h, a0l, x1h, x1l, x2h, x2l, er, ei);

    for (int i = 0; i < 4; ++i) {
        const short* xh = (i == 0) ? a0h : x1h;
        const short* xl = (i == 0) ? a0l : x1l;
        hipLaunchKernelGGL(gemm_k, dim3(64, SPLITK), dim3(256), 0, stream,
                           xh, xl, gatW + (size_t)i * DIM * DIM, hpart);
        hipLaunchKernelGGL(hsum_k, dim3(216), dim3(256), 0, stream, hpart, hsum);
        hipLaunchKernelGGL(dots_k, dim3(54), dim3(256), 0, stream,
                           hsum, attif + (size_t)i * 2 * DIM, attfd + (size_t)i * 2 * DIM,
                           attdr + (size_t)i * 2 * DIM, dots);
        hipLaunchKernelGGL(tmat_k, dim3(1), dim3(64), 0, stream, dots, Tm);
        hipLaunchKernelGGL(applyT_k, dim3(16, 54), dim3(256), 0, stream, hsum, Tm, x2h, x2l);
        hipLaunchKernelGGL(gemm_k, dim3(64, SPLITK), dim3(256), 0, stream,
                           x2h, x2l, metaW + (size_t)i * DIM * DIM, hpart);
        hipLaunchKernelGGL(hsum_k, dim3(216), dim3(256), 0, stream, hpart, hsum);
        hipLaunchKernelGGL(rope_k, dim3(8, 54), dim3(256), 0, stream,
                           hsum, er, ei, x1h, x1l, out, (i == 3) ? 1 : 0);
    }
}